// Round 1
// baseline (294.721 us; speedup 1.0000x reference)
//
#include <hip/hip_runtime.h>
#include <hip/hip_bf16.h>

typedef __bf16 bf16;
typedef __attribute__((ext_vector_type(8))) __bf16 bf16x8;
typedef __attribute__((ext_vector_type(4))) __bf16 bf16x4;
typedef __attribute__((ext_vector_type(4))) float floatx4;

// ---------------------------------------------------------------- cast fp32 -> bf16 (x4 vectorized)
__global__ __launch_bounds__(256) void cast_f32_bf16_v4(const float* __restrict__ in,
                                                        bf16* __restrict__ out,
                                                        long long n4) {
    long long i = (long long)blockIdx.x * 256 + threadIdx.x;
    if (i < n4) {
        float4 v = ((const float4*)in)[i];
        bf16x4 o;
        o[0] = (bf16)v.x; o[1] = (bf16)v.y; o[2] = (bf16)v.z; o[3] = (bf16)v.w;
        ((bf16x4*)out)[i] = o;
    }
}

// ---------------------------------------------------------------- generic 64x64-tile MFMA GEMM
// C[M,N] = op(A[M,K] * B)   A row-major.
// TRANSB: B is [N,K] row-major (dot of rows)  else B is [K,N] row-major.
// TANH: apply tanhf to result. OUTBF16: store bf16 else fp32.
// blockIdx.z batches with given element strides.
template <bool TRANSB, bool TANH, bool OUTBF16>
__global__ __launch_bounds__(256) void gemm64(const bf16* __restrict__ A,
                                              const bf16* __restrict__ Bm,
                                              void* __restrict__ Cout,
                                              int M, int N, int K,
                                              long long batchA, long long batchB, long long batchC) {
    const long long bz = blockIdx.z;
    A  += bz * batchA;
    Bm += bz * batchB;

    const int m0 = blockIdx.x * 64;
    const int n0 = blockIdx.y * 64;

    __shared__ bf16 As[64][40];   // row stride 80 B: 16B-aligned, 20-dword bank stride (2-way max)
    __shared__ bf16 Bs[64][40];

    const int t    = threadIdx.x;
    const int lane = t & 63;
    const int wave = t >> 6;
    const int quad = lane >> 4;
    const int l16  = lane & 15;
    const int wm   = (wave >> 1) * 32;
    const int wn   = (wave & 1) * 32;

    floatx4 acc[2][2] = {};

    for (int k0 = 0; k0 < K; k0 += 32) {
        // ---- stage A: 64 rows x 32 k, each thread one 16B chunk
        {
            int r = t >> 2, c = (t & 3) * 8;
            const bf16* src = A + (long long)(m0 + r) * K + (k0 + c);
            *(bf16x8*)(&As[r][c]) = *(const bf16x8*)src;
        }
        // ---- stage B
        if (TRANSB) {
            int r = t >> 2, c = (t & 3) * 8;
            const bf16* src = Bm + (long long)(n0 + r) * K + (k0 + c);
            *(bf16x8*)(&Bs[r][c]) = *(const bf16x8*)src;
        } else {
            // B is [K,N]: transpose into Bs[n][k]; coalesced reads (lanes sweep n), one 16B LDS write
            int n = t & 63, kg = (t >> 6) * 8;
            bf16x8 tmp;
#pragma unroll
            for (int j = 0; j < 8; ++j)
                tmp[j] = Bm[(long long)(k0 + kg + j) * N + (n0 + n)];
            *(bf16x8*)(&Bs[n][kg]) = tmp;
        }
        __syncthreads();

        bf16x8 af[2], bfr[2];
#pragma unroll
        for (int i = 0; i < 2; ++i)
            af[i] = *(const bf16x8*)(&As[wm + i * 16 + l16][quad * 8]);
#pragma unroll
        for (int j = 0; j < 2; ++j)
            bfr[j] = *(const bf16x8*)(&Bs[wn + j * 16 + l16][quad * 8]);

#pragma unroll
        for (int i = 0; i < 2; ++i)
#pragma unroll
            for (int j = 0; j < 2; ++j)
                acc[i][j] = __builtin_amdgcn_mfma_f32_16x16x32_bf16(af[i], bfr[j], acc[i][j], 0, 0, 0);

        __syncthreads();
    }

    // ---- epilogue: D[row = quad*4+r][col = l16] per 16x16 tile
#pragma unroll
    for (int i = 0; i < 2; ++i) {
#pragma unroll
        for (int j = 0; j < 2; ++j) {
#pragma unroll
            for (int r = 0; r < 4; ++r) {
                long long row = m0 + wm + i * 16 + quad * 4 + r;
                long long col = n0 + wn + j * 16 + l16;
                float v = acc[i][j][r];
                if (TANH) v = tanhf(v);
                if (OUTBF16)
                    ((bf16*)Cout)[bz * batchC + row * N + col] = (bf16)v;
                else
                    ((float*)Cout)[bz * batchC + row * N + col] = v;
            }
        }
    }
}

// ---------------------------------------------------------------- row softmax over 2048 bf16, in place
__device__ __forceinline__ float waveRedMax(float v) {
#pragma unroll
    for (int o = 32; o > 0; o >>= 1) v = fmaxf(v, __shfl_xor(v, o));
    return v;
}
__device__ __forceinline__ float waveRedSum(float v) {
#pragma unroll
    for (int o = 32; o > 0; o >>= 1) v += __shfl_xor(v, o);
    return v;
}

__global__ __launch_bounds__(256) void softmax2048(bf16* __restrict__ Sb, long long batchS) {
    bf16* row = Sb + blockIdx.z * batchS + (long long)blockIdx.x * 2048;
    const int t = threadIdx.x;
    const int lane = t & 63, wave = t >> 6;

    bf16x8 pack = ((const bf16x8*)row)[t];
    float v[8];
    float mx = -1e30f;
#pragma unroll
    for (int j = 0; j < 8; ++j) { v[j] = (float)pack[j]; mx = fmaxf(mx, v[j]); }

    __shared__ float smax[4], ssum[4];
    mx = waveRedMax(mx);
    if (lane == 0) smax[wave] = mx;
    __syncthreads();
    mx = fmaxf(fmaxf(smax[0], smax[1]), fmaxf(smax[2], smax[3]));

    float s = 0.f;
#pragma unroll
    for (int j = 0; j < 8; ++j) { v[j] = __expf(v[j] - mx); s += v[j]; }
    s = waveRedSum(s);
    if (lane == 0) ssum[wave] = s;
    __syncthreads();
    s = ssum[0] + ssum[1] + ssum[2] + ssum[3];
    float inv = 1.0f / s;

    bf16x8 o;
#pragma unroll
    for (int j = 0; j < 8; ++j) o[j] = (bf16)(v[j] * inv);
    ((bf16x8*)row)[t] = o;
}

// ----------------------------------------------------------------
extern "C" void kernel_launch(void* const* d_in, const int* in_sizes, int n_in,
                              void* d_out, int out_size, void* d_ws, size_t ws_size,
                              hipStream_t stream) {
    const int B = 8, S = 2048, D = 512;
    const float* x = (const float*)d_in[0];
    const float* W = (const float*)d_in[1];
    float* out = (float*)d_out;

    const size_t nx = (size_t)B * S * D;  // 8388608
    const size_t nw = (size_t)D * D;      // 262144

    char* ws = (char*)d_ws;
    auto al = [](size_t v) { return (v + 255) & ~(size_t)255; };
    size_t off = 0;
    bf16* xb = (bf16*)(ws + off); off = al(off + nx * 2);
    bf16* pb = (bf16*)(ws + off); off = al(off + nx * 2);
    bf16* wb = (bf16*)(ws + off); off = al(off + nw * 2);
    bf16* sb = (bf16*)(ws + off);
    const size_t full_need  = off + (size_t)B * S * S * 2;  // ~102 MB
    const bool batched = (ws_size >= full_need);

    // casts
    cast_f32_bf16_v4<<<(int)((nx / 4 + 255) / 256), 256, 0, stream>>>(x, xb, (long long)(nx / 4));
    cast_f32_bf16_v4<<<(int)((nw / 4 + 255) / 256), 256, 0, stream>>>(W, wb, (long long)(nw / 4));

    // proj: pb[BS,D] = xb[BS,D] @ wb[D,D]   (NN)
    {
        dim3 g(B * S / 64, D / 64, 1);
        gemm64<false, false, true><<<g, 256, 0, stream>>>(xb, wb, (void*)pb, B * S, D, D, 0, 0, 0);
    }

    const long long sd = (long long)S * D;
    const long long ss = (long long)S * S;

    if (batched) {
        // scores: sb[b] = tanh(pb[b] @ xb[b]^T)   (NT)
        dim3 g2(S / 64, S / 64, B);
        gemm64<true, true, true><<<g2, 256, 0, stream>>>(pb, xb, (void*)sb, S, S, D, sd, sd, ss);
        dim3 g3(S, 1, B);
        softmax2048<<<g3, 256, 0, stream>>>(sb, ss);
        dim3 g4(S / 64, D / 64, B);
        gemm64<false, false, false><<<g4, 256, 0, stream>>>(sb, xb, (void*)out, S, D, S, ss, sd, sd);
    } else {
        for (int b = 0; b < B; ++b) {
            dim3 g2(S / 64, S / 64, 1);
            gemm64<true, true, true><<<g2, 256, 0, stream>>>(pb + (size_t)b * sd, xb + (size_t)b * sd,
                                                            (void*)sb, S, S, D, 0, 0, 0);
            dim3 g3(S, 1, 1);
            softmax2048<<<g3, 256, 0, stream>>>(sb, 0);
            dim3 g4(S / 64, D / 64, 1);
            gemm64<false, false, false><<<g4, 256, 0, stream>>>(sb, xb + (size_t)b * sd,
                                                                (void*)(out + (size_t)b * sd), S, D, S, 0, 0, 0);
        }
    }
}

// Round 2
// 247.958 us; speedup vs baseline: 1.1886x; 1.1886x over previous
//
#include <hip/hip_runtime.h>
#include <hip/hip_bf16.h>

typedef __bf16 bf16;
typedef __attribute__((ext_vector_type(8))) __bf16 bf16x8;
typedef __attribute__((ext_vector_type(4))) __bf16 bf16x4;
typedef __attribute__((ext_vector_type(4))) float floatx4;

// async global->LDS, 16B per lane. LDS dest must be wave-uniform base + lane*16.
__device__ __forceinline__ void gl_lds16(const bf16* g, bf16* l) {
    __builtin_amdgcn_global_load_lds(
        (const __attribute__((address_space(1))) unsigned int*)g,
        (__attribute__((address_space(3))) unsigned int*)l,
        16, 0, 0);
}

// ---------------------------------------------------------------- cast fp32 -> bf16 (x4 vectorized)
__global__ __launch_bounds__(256) void cast_f32_bf16_v4(const float* __restrict__ in,
                                                        bf16* __restrict__ out,
                                                        long long n4) {
    long long i = (long long)blockIdx.x * 256 + threadIdx.x;
    if (i < n4) {
        float4 v = ((const float4*)in)[i];
        bf16x4 o;
        o[0] = (bf16)v.x; o[1] = (bf16)v.y; o[2] = (bf16)v.z; o[3] = (bf16)v.w;
        ((bf16x4*)out)[i] = o;
    }
}

// ---------------------------------------------------------------- fp32 [R,C] -> bf16 [C,R] transpose
// block 256 = 32x8, 32x32 tile, padded LDS. blockIdx.z batches (stride R*C both sides).
__global__ __launch_bounds__(256) void cast_transpose(const float* __restrict__ in,
                                                      bf16* __restrict__ out,
                                                      int R, int C) {
    __shared__ float tile[32][33];
    const long long bz = blockIdx.z;
    in  += bz * (long long)R * C;
    out += bz * (long long)R * C;
    const int r0 = blockIdx.x * 32, c0 = blockIdx.y * 32;
    const int tx = threadIdx.x & 31, ty = threadIdx.x >> 5;
#pragma unroll
    for (int i = 0; i < 32; i += 8)
        tile[ty + i][tx] = in[(long long)(r0 + ty + i) * C + (c0 + tx)];
    __syncthreads();
#pragma unroll
    for (int i = 0; i < 32; i += 8)
        out[(long long)(c0 + ty + i) * R + (r0 + tx)] = (bf16)tile[tx][ty + i];
}

__device__ __forceinline__ float fast_tanh(float v) {
    // 1 - 2/(e^{2v}+1): safe at +-inf (exp overflow -> 1, underflow -> -1)
    float e = __expf(2.0f * v);
    return 1.0f - 2.0f / (e + 1.0f);
}

// ---------------------------------------------------------------- 128x128-tile MFMA GEMM, NT form
// C[M,N] = op(A[M,K] * B[N,K]^T); A,B row-major bf16, K % 32 == 0, M,N % 128 == 0.
// global_load_lds (16B) staging, 4 waves each computing a 64x64 quadrant (4x4 MFMA 16x16x32).
template <bool TANH, bool OUTBF16>
__global__ __launch_bounds__(256) void gemm128_nt(const bf16* __restrict__ A,
                                                  const bf16* __restrict__ Bm,
                                                  void* __restrict__ Cout,
                                                  int M, int N, int K,
                                                  long long batchA, long long batchB, long long batchC) {
    const long long bz = blockIdx.z;
    A  += bz * batchA;
    Bm += bz * batchB;

    __shared__ bf16 As[128 * 32];   // unpadded: required by global_load_lds lane layout
    __shared__ bf16 Bs[128 * 32];

    const int t    = threadIdx.x;
    const int lane = t & 63;
    const int wave = t >> 6;
    const int quad = lane >> 4;
    const int l16  = lane & 15;

    const int m0 = blockIdx.x * 128;
    const int n0 = blockIdx.y * 128;
    const int wm = (wave >> 1) * 64;
    const int wn = (wave & 1) * 64;

    floatx4 acc[4][4] = {};

    // staging: chunk ch in [0,512): row = ch>>2, col = (ch&3)*8 ; thread t does ch = t, t+256.
    const int r0 = t >> 2;             // 0..63
    const int c0 = (t & 3) * 8;        // 0/8/16/24

    const bf16* Ag0 = A + (long long)(m0 + r0) * K + c0;
    const bf16* Ag1 = A + (long long)(m0 + 64 + r0) * K + c0;
    const bf16* Bg0 = Bm + (long long)(n0 + r0) * K + c0;
    const bf16* Bg1 = Bm + (long long)(n0 + 64 + r0) * K + c0;

    for (int k0 = 0; k0 < K; k0 += 32) {
        gl_lds16(Ag0 + k0, &As[t * 8]);
        gl_lds16(Ag1 + k0, &As[(t + 256) * 8]);
        gl_lds16(Bg0 + k0, &Bs[t * 8]);
        gl_lds16(Bg1 + k0, &Bs[(t + 256) * 8]);
        __syncthreads();   // drains vmcnt (global_load_lds) before LDS reads

        bf16x8 af[4], bfr[4];
#pragma unroll
        for (int i = 0; i < 4; ++i)
            af[i] = *(const bf16x8*)(&As[(wm + i * 16 + l16) * 32 + quad * 8]);
#pragma unroll
        for (int j = 0; j < 4; ++j)
            bfr[j] = *(const bf16x8*)(&Bs[(wn + j * 16 + l16) * 32 + quad * 8]);

#pragma unroll
        for (int i = 0; i < 4; ++i)
#pragma unroll
            for (int j = 0; j < 4; ++j)
                acc[i][j] = __builtin_amdgcn_mfma_f32_16x16x32_bf16(af[i], bfr[j], acc[i][j], 0, 0, 0);

        __syncthreads();
    }

    // epilogue: per 16x16 tile, D[row = quad*4+r][col = l16]
#pragma unroll
    for (int i = 0; i < 4; ++i) {
#pragma unroll
        for (int j = 0; j < 4; ++j) {
#pragma unroll
            for (int r = 0; r < 4; ++r) {
                long long row = m0 + wm + i * 16 + quad * 4 + r;
                long long col = n0 + wn + j * 16 + l16;
                float v = acc[i][j][r];
                if (TANH) v = fast_tanh(v);
                if (OUTBF16)
                    ((bf16*)Cout)[bz * batchC + row * (long long)N + col] = (bf16)v;
                else
                    ((float*)Cout)[bz * batchC + row * (long long)N + col] = v;
            }
        }
    }
}

// ---------------------------------------------------------------- row softmax over 2048 bf16, in place
__device__ __forceinline__ float waveRedMax(float v) {
#pragma unroll
    for (int o = 32; o > 0; o >>= 1) v = fmaxf(v, __shfl_xor(v, o));
    return v;
}
__device__ __forceinline__ float waveRedSum(float v) {
#pragma unroll
    for (int o = 32; o > 0; o >>= 1) v += __shfl_xor(v, o);
    return v;
}

__global__ __launch_bounds__(256) void softmax2048(bf16* __restrict__ Sb, long long batchS) {
    bf16* row = Sb + blockIdx.z * batchS + (long long)blockIdx.x * 2048;
    const int t = threadIdx.x;
    const int lane = t & 63, wave = t >> 6;

    bf16x8 pack = ((const bf16x8*)row)[t];
    float v[8];
    float mx = -1e30f;
#pragma unroll
    for (int j = 0; j < 8; ++j) { v[j] = (float)pack[j]; mx = fmaxf(mx, v[j]); }

    __shared__ float smax[4], ssum[4];
    mx = waveRedMax(mx);
    if (lane == 0) smax[wave] = mx;
    __syncthreads();
    mx = fmaxf(fmaxf(smax[0], smax[1]), fmaxf(smax[2], smax[3]));

    float s = 0.f;
#pragma unroll
    for (int j = 0; j < 8; ++j) { v[j] = __expf(v[j] - mx); s += v[j]; }
    s = waveRedSum(s);
    if (lane == 0) ssum[wave] = s;
    __syncthreads();
    s = ssum[0] + ssum[1] + ssum[2] + ssum[3];
    float inv = 1.0f / s;

    bf16x8 o;
#pragma unroll
    for (int j = 0; j < 8; ++j) o[j] = (bf16)(v[j] * inv);
    ((bf16x8*)row)[t] = o;
}

// ----------------------------------------------------------------
extern "C" void kernel_launch(void* const* d_in, const int* in_sizes, int n_in,
                              void* d_out, int out_size, void* d_ws, size_t ws_size,
                              hipStream_t stream) {
    const int B = 8, S = 2048, D = 512;
    const float* x = (const float*)d_in[0];
    const float* W = (const float*)d_in[1];
    float* out = (float*)d_out;

    const size_t nx = (size_t)B * S * D;  // 8388608
    const size_t nw = (size_t)D * D;      // 262144

    char* ws = (char*)d_ws;
    auto al = [](size_t v) { return (v + 255) & ~(size_t)255; };
    size_t off = 0;
    bf16* xb = (bf16*)(ws + off); off = al(off + nx * 2);   // x bf16 [B,S,D]
    bf16* xt = (bf16*)(ws + off); off = al(off + nx * 2);   // x^T bf16 [B,D,S]
    bf16* pb = (bf16*)(ws + off); off = al(off + nx * 2);   // proj bf16 [B,S,D]
    bf16* wt = (bf16*)(ws + off); off = al(off + nw * 2);   // W^T bf16 [D,D]
    bf16* sb = (bf16*)(ws + off);                           // scores bf16
    const size_t full_need = off + (size_t)B * S * S * 2;   // ~118 MB
    const bool batched = (ws_size >= full_need);

    // xb = bf16(x); xt = bf16(x)^T per batch; wt = bf16(W)^T
    cast_f32_bf16_v4<<<(int)((nx / 4 + 255) / 256), 256, 0, stream>>>(x, xb, (long long)(nx / 4));
    { dim3 g(S / 32, D / 32, B); cast_transpose<<<g, 256, 0, stream>>>(x, xt, S, D); }
    { dim3 g(D / 32, D / 32, 1); cast_transpose<<<g, 256, 0, stream>>>(W, wt, D, D); }

    // proj: pb[BS,D] = xb[BS,D] @ wt[D,D]^T
    {
        dim3 g(B * S / 128, D / 128, 1);
        gemm128_nt<false, true><<<g, 256, 0, stream>>>(xb, wt, (void*)pb, B * S, D, D, 0, 0, 0);
    }

    const long long sd = (long long)S * D;
    const long long ss = (long long)S * S;

    if (batched) {
        // scores: sb[b] = tanh(pb[b] @ xb[b]^T)
        dim3 g2(S / 128, S / 128, B);
        gemm128_nt<true, true><<<g2, 256, 0, stream>>>(pb, xb, (void*)sb, S, S, D, sd, sd, ss);
        dim3 g3(S, 1, B);
        softmax2048<<<g3, 256, 0, stream>>>(sb, ss);
        // out[b] = attn[b] @ xt[b]^T   (xt rows over K=S)
        dim3 g4(S / 128, D / 128, B);
        gemm128_nt<false, false><<<g4, 256, 0, stream>>>(sb, xt, (void*)out, S, D, S, ss, sd, sd);
    } else {
        for (int b = 0; b < B; ++b) {
            dim3 g2(S / 128, S / 128, 1);
            gemm128_nt<true, true><<<g2, 256, 0, stream>>>(pb + (size_t)b * sd, xb + (size_t)b * sd,
                                                          (void*)sb, S, S, D, 0, 0, 0);
            dim3 g3(S, 1, 1);
            softmax2048<<<g3, 256, 0, stream>>>(sb, 0);
            dim3 g4(S / 128, D / 128, 1);
            gemm128_nt<false, false><<<g4, 256, 0, stream>>>(sb, xt + (size_t)b * sd,
                                                             (void*)(out + (size_t)b * sd), S, D, S, 0, 0, 0);
        }
    }
}